// Round 10
// baseline (293.339 us; speedup 1.0000x reference)
//
#include <hip/hip_runtime.h>
#include <stdint.h>

#define T_    4096
#define XGS   74      // xs g-stride (u32): 9 u-slots * 8 d-pairs + 2 pad
#define ATS16 2112    // As t-stride (u16) = 32*66
#define AIS16 66      // As i-stride (u16)
#define CTS16 1056    // Cs t-stride (u16) = 16*66
#define CSB16 16896   // Cs base offset in ACs16 (u16 units) = 8*2112
#define RSW   33      // rs t-stride (f32)

typedef _Float16 h2 __attribute__((ext_vector_type(2)));

static __device__ __forceinline__ float dot2(uint32_t a, uint32_t b, float c) {
#if __has_builtin(__builtin_amdgcn_fdot2)
    return __builtin_amdgcn_fdot2(__builtin_bit_cast(h2, a), __builtin_bit_cast(h2, b), c, false);
#else
    h2 ha = __builtin_bit_cast(h2, a), hb = __builtin_bit_cast(h2, b);
    return fmaf((float)ha.x, (float)hb.x, fmaf((float)ha.y, (float)hb.y, c));
#endif
}
static __device__ __forceinline__ float exp2a(float x) {
#if __has_builtin(__builtin_amdgcn_exp2f)
    return __builtin_amdgcn_exp2f(x);
#else
    return exp2f(x);
#endif
}
static __device__ __forceinline__ uint16_t f2h(float f) {
    _Float16 h = (_Float16)f; return __builtin_bit_cast(uint16_t, h);
}
static __device__ __forceinline__ float h2f(uint16_t u) {
    return (float)__builtin_bit_cast(_Float16, u);
}
static __device__ __forceinline__ uint32_t pk2(float lo, float hi) {
    return __builtin_bit_cast(uint32_t, __builtin_amdgcn_cvt_pkrtz(lo, hi));
}
// out-stage (u32 = f16 d-pair): idx = 9*rp + 2*(rp>>4) + t, t in 0..7.
// Injective: rp step >= 9 > t span 7. Max = 9*255 + 30 + 7 = 2332 < 2336.
static __device__ __forceinline__ int stg_ix(int rp, int t) {
    return rp * 9 + 2 * (rp >> 4) + t;
}

__global__ __launch_bounds__(1024, 4)
void tamcad_kernel(const float* __restrict__ x, const float* __restrict__ W,
                   const float* __restrict__ bias, float* __restrict__ out)
{
    __shared__ uint16_t ACs16[CSB16 + 8 * CTS16];  // 50,688B: As[t][i][j] | Cs[t][d][j]
    __shared__ uint32_t xs32[2368];                //  9,472B: x f16 d-pairs [g][u][dp]
    __shared__ uint32_t stg [2336];                //  9,344B: out staging, f16 d-pairs
    __shared__ float    rs  [264];                 //  1,056B: rcp(rowsum) [t][i]
    const uint32_t* As32r = (const uint32_t*)ACs16;
    const uint32_t* Cs32r = (const uint32_t*)(ACs16 + CSB16);

    const int tid   = threadIdx.x;
    const int bk    = blockIdx.x >> 6;   // 0..7
    const int chunk = blockIdx.x & 63;   // 0..63
    const int b     = bk >> 1;
    const int k     = bk & 1;

    const int g  = tid >> 5;             // group 0..31
    const int m  = tid & 31;             // lane in group
    const int d  = m >> 1;               // P0 d-lane 0..15
    const int h  = m & 1;                // P0 u-half
    const int oq = m;                    // P1 o-slice (3 o's each)
    const int slot = m >> 4;             // 0: u=t (o<48), 1: u=t+1 (o>=48)

    // ---- W as packed f16 pairs (3 x 8 u32), bias, branchless store routing ----
    uint32_t wp2[3][8]; float breg[3]; int sofs[3]; bool isl[3];
    #pragma unroll
    for (int r = 0; r < 3; ++r) {
        const int o = oq * 3 + r;
        const float4* wp = reinterpret_cast<const float4*>(W + (((size_t)(k*32+g))*96 + o)*16);
        float4 w0 = wp[0], w1 = wp[1], w2 = wp[2], w3 = wp[3];
        wp2[r][0] = pk2(w0.x, w0.y); wp2[r][1] = pk2(w0.z, w0.w);
        wp2[r][2] = pk2(w1.x, w1.y); wp2[r][3] = pk2(w1.z, w1.w);
        wp2[r][4] = pk2(w2.x, w2.y); wp2[r][5] = pk2(w2.z, w2.w);
        wp2[r][6] = pk2(w3.x, w3.y); wp2[r][7] = pk2(w3.z, w3.w);
        breg[r] = bias[(k*32+g)*96 + o];
        if (o < 32)      { isl[r] = true;  sofs[r] = g*AIS16 + o; }
        else if (o < 48) { isl[r] = false; sofs[r] = CSB16 + (o-32)*AIS16 + g; }
        else if (o < 80) { isl[r] = true;  sofs[r] = g*AIS16 + (o-16); }
        else             { isl[r] = false; sofs[r] = CSB16 + (o-80)*AIS16 + 32 + g; }
    }

    const float* xrow = x + ((size_t)b*1024 + (size_t)(k*32+g)*16 + d) * (size_t)T_;

    // prologue: tile-0 loads. h=0 -> u0..3; h=1 -> u4..7 + u8 (chunk*64+8 <= 4040, in-bounds)
    float4 pA; float pS;
    {
        const float* gp = xrow + chunk*64 + h*4;
        pA = *(const float4*)gp;
        pS = h ? gp[4] : 0.0f;
    }

    for (int l = 0; l <= 8; ++l) {
        const int t0p = chunk*64 + (l-1)*8;   // drained tile (valid when l>0)

        // ================= Phase A =================
        if (l > 0) {
            if (tid < 512) {
                // ---- P3: out[i,d,t] = rinv * sum_j e'[i,j] y[j,d]; acc[2][4]
                const int t  = tid >> 6;             // 0..7
                const int r6 = tid & 63;
                const int i0 = (r6 & 15) * 2;        // 0,2,..,30
                const int d0 = (r6 >> 4) * 4;        // 0,4,8,12
                const int ab = t*1056 + i0*33;
                const int cb = t*528  + d0*33;
                float acc[2][4];
                #pragma unroll
                for (int ii = 0; ii < 2; ++ii)
                    #pragma unroll
                    for (int dd = 0; dd < 4; ++dd) acc[ii][dd] = 0.f;
                #pragma unroll 4
                for (int jp = 0; jp < 32; ++jp) {
                    uint32_t a0 = As32r[ab+jp],    a1 = As32r[ab+33+jp];
                    uint32_t c0 = Cs32r[cb+jp],    c1 = Cs32r[cb+33+jp];
                    uint32_t c2 = Cs32r[cb+66+jp], c3 = Cs32r[cb+99+jp];
                    acc[0][0]=dot2(a0,c0,acc[0][0]); acc[0][1]=dot2(a0,c1,acc[0][1]);
                    acc[0][2]=dot2(a0,c2,acc[0][2]); acc[0][3]=dot2(a0,c3,acc[0][3]);
                    acc[1][0]=dot2(a1,c0,acc[1][0]); acc[1][1]=dot2(a1,c1,acc[1][1]);
                    acc[1][2]=dot2(a1,c2,acc[1][2]); acc[1][3]=dot2(a1,c3,acc[1][3]);
                }
                const float rv0 = rs[t*RSW + i0], rv1 = rs[t*RSW + i0 + 1];
                const int rp0 = i0*8 + (d0 >> 1);
                stg[stg_ix(rp0,     t)] = pk2(acc[0][0]*rv0, acc[0][1]*rv0);
                stg[stg_ix(rp0 + 1, t)] = pk2(acc[0][2]*rv0, acc[0][3]*rv0);
                stg[stg_ix(rp0 + 8, t)] = pk2(acc[1][0]*rv1, acc[1][1]*rv1);
                stg[stg_ix(rp0 + 9, t)] = pk2(acc[1][2]*rv1, acc[1][3]*rv1);
            } else {
                // ---- P4a: attn global writes (u32 j-pair reads, broadcast-free)
                const int q = tid - 512, j = q & 63, jb = j >> 1, jh = j & 1;
                const int ib = q >> 6;               // 0..7
                float* attn_base = out + (size_t)4*1024*(size_t)T_;
                #pragma unroll
                for (int rr = 0; rr < 4; ++rr) {
                    const int i = ib + 8*rr;
                    float av[8];
                    #pragma unroll
                    for (int u = 0; u < 8; ++u) {
                        uint32_t w = As32r[u*1056 + i*33 + jb];
                        av[u] = h2f(jh ? (uint16_t)(w >> 16) : (uint16_t)(w & 0xFFFF))
                              * rs[u*RSW + i];
                    }
                    float* tp2 = attn_base + (((size_t)bk*32 + i)*64 + j)*(size_t)T_ + t0p;
                    *(float4*)(tp2+0) = make_float4(av[0],av[1],av[2],av[3]);
                    *(float4*)(tp2+4) = make_float4(av[4],av[5],av[6],av[7]);
                }
            }
        }
        if (l < 8) {
            // ---- P0: pack f32 -> f16 d-pairs via lane-xor(2), stage into xs
            float va[5] = { pA.x, pA.y, pA.z, pA.w, pS };
            #pragma unroll
            for (int i = 0; i < 5; ++i) {
                if (i == 4 && h == 0) continue;
                const int u = h*4 + i;
                const float mine  = va[i];
                const float other = __shfl_xor(mine, 2);
                if (((u ^ d) & 1) == 0) {            // u parity == d parity
                    const uint32_t pk = (d & 1) ? pk2(other, mine) : pk2(mine, other);
                    xs32[g*XGS + u*8 + (d >> 1)] = pk;
                }
            }
            if (l < 7) {                             // issue tile l+1 loads
                const int t0n = chunk*64 + (l+1)*8;
                const float* gp = xrow + t0n + h*4;
                pA = *(const float4*)gp;
                pS = (h && (t0n + 8) < T_) ? gp[4] : 0.0f;
            }
        }
        __syncthreads();

        // ================= Phase B =================
        if (l > 0) {
            // ---- P4b: out global writes (drain under P1)
            const int r   = tid >> 1;                // out row 0..511
            const int th4 = (tid & 1) * 4;           // t-half
            const int rp  = r >> 1, hi = r & 1;
            const int base = stg_ix(rp, th4);
            float ov[4];
            #pragma unroll
            for (int u = 0; u < 4; ++u) {
                uint32_t w = stg[base + u];
                ov[u] = h2f(hi ? (uint16_t)(w >> 16) : (uint16_t)(w & 0xFFFF));
            }
            float* op = out + ((size_t)b*1024 + k*512 + r)*(size_t)T_ + t0p + th4;
            *(float4*)op = make_float4(ov[0], ov[1], ov[2], ov[3]);
        }
        if (l < 8) {
            // ---- P1: y = W.x + b (dot2); no-max softmax; u16 routed stores
            float asum[8];
            #pragma unroll
            for (int q = 0; q < 8; ++q) {
                const uint32_t* xp = xs32 + g*XGS + (q + slot)*8;
                uint4 xa = *(const uint4*)xp;
                uint4 xb = *(const uint4*)(xp + 4);
                uint32_t xw[8] = { xa.x,xa.y,xa.z,xa.w, xb.x,xb.y,xb.z,xb.w };
                float s = 0.f;
                #pragma unroll
                for (int r = 0; r < 3; ++r) {
                    float y = breg[r];
                    #pragma unroll
                    for (int dd = 0; dd < 8; ++dd) y = dot2(wp2[r][dd], xw[dd], y);
                    // e' = 2^(y*log2e - 4) = exp(y)/16 (f16-safe to y ~ 13.9)
                    const float e = exp2a(fmaf(y, 1.44269504089f, -4.0f));
                    s += isl[r] ? e : 0.f;
                    ACs16[sofs[r] + q*(isl[r] ? ATS16 : CTS16)] = f2h(isl[r] ? e : y);
                }
                asum[q] = s;
            }
            #pragma unroll
            for (int sft = 1; sft < 32; sft <<= 1) {
                #pragma unroll
                for (int q = 0; q < 8; ++q) asum[q] += __shfl_xor(asum[q], sft);
            }
            if (oq == 0) {
                #pragma unroll
                for (int q = 0; q < 8; ++q)
                    rs[q*RSW + g] = __builtin_amdgcn_rcpf(asum[q]);
            }
        }
        if (l < 8) __syncthreads();
    }
}

extern "C" void kernel_launch(void* const* d_in, const int* in_sizes, int n_in,
                              void* d_out, int out_size, void* d_ws, size_t ws_size,
                              hipStream_t stream) {
    const float* x  = (const float*)d_in[0];
    const float* W  = (const float*)d_in[1];
    const float* bs = (const float*)d_in[2];
    float* out = (float*)d_out;
    tamcad_kernel<<<dim3(512), dim3(1024), 0, stream>>>(x, W, bs, out);
}